// Round 12
// baseline (416.403 us; speedup 1.0000x reference)
//
#include <hip/hip_runtime.h>
#include <hip/hip_bf16.h>

typedef __attribute__((ext_vector_type(8))) short short8;
typedef __attribute__((ext_vector_type(4))) float f32x4;

__device__ __forceinline__ unsigned short fbf(float f) {
  union { float f; unsigned u; } v; v.f = f;
  unsigned r = v.u + 0x7fffu + ((v.u >> 16) & 1u);   // RNE
  return (unsigned short)(r >> 16);
}
__device__ __forceinline__ unsigned pk2(float a, float b) {
  return (unsigned)fbf(a) | ((unsigned)fbf(b) << 16);
}
__device__ __forceinline__ float ubf(unsigned hi) {   // bf16 bits (low16) -> float
  union { unsigned u; float f; } v; v.u = hi << 16; return v.f;
}
__device__ __forceinline__ float ubf_lo(unsigned u) { // low16 bf16 -> float
  union { unsigned u; float f; } v; v.u = u << 16; return v.f;
}
__device__ __forceinline__ float ubf_hi(unsigned u) { // high16 bf16 -> float
  union { unsigned u; float f; } v; v.u = u & 0xffff0000u; return v.f;
}
__device__ __forceinline__ float dot4(float4 a, float4 b) {
  return fmaf(a.x, b.x, fmaf(a.y, b.y, fmaf(a.z, b.z, a.w * b.w)));
}

// -------- phase1: degree count + A_s/A_d tables + x->bf16 (single x pass) --------
__launch_bounds__(256)
__global__ void k_phase1(const float* __restrict__ x, const float* __restrict__ W_att,
                         const int* __restrict__ edst, int E,
                         float4* __restrict__ A_s, float4* __restrict__ A_d,
                         unsigned* __restrict__ xb32, int* __restrict__ deg, int N) {
  __shared__ float4 s_wa[160];                 // 4 heads x 40 float4 (row len 160)
  if (threadIdx.x < 160) s_wa[threadIdx.x] = ((const float4*)W_att)[threadIdx.x];
  for (int i = blockIdx.x * blockDim.x + threadIdx.x; i < E; i += gridDim.x * blockDim.x)
    atomicAdd(&deg[edst[i]], 1);
  __syncthreads();
  for (int v = blockIdx.x * blockDim.x + threadIdx.x; v < N; v += gridDim.x * blockDim.x) {
    const float4* xp = (const float4*)&x[v * 64];
    float4 xq[16];
    #pragma unroll
    for (int k = 0; k < 16; k++) xq[k] = xp[k];
    float as[4] = {}, ad[4] = {};
    #pragma unroll
    for (int h = 0; h < 4; h++) {
      #pragma unroll
      for (int k = 0; k < 16; k++) {
        as[h] += dot4(s_wa[h * 40 + k], xq[k]);
        ad[h] += dot4(s_wa[h * 40 + 16 + k], xq[k]);
      }
    }
    A_s[v] = make_float4(as[0], as[1], as[2], as[3]);
    A_d[v] = make_float4(ad[0], ad[1], ad[2], ad[3]);
    #pragma unroll
    for (int k = 0; k < 16; k++) {
      xb32[v * 32 + 2 * k]     = pk2(xq[k].x, xq[k].y);
      xb32[v * 32 + 2 * k + 1] = pk2(xq[k].z, xq[k].w);
    }
  }
}

// -------- scans over PADDED degrees (each node region rounded to mult of 8) --------
__global__ void k_scan1(const int* __restrict__ deg, int N, int* __restrict__ part,
                        int* __restrict__ bsum) {
  __shared__ int tmp[1024];
  int tid = threadIdx.x;
  int i = blockIdx.x * 1024 + tid;
  int dv = (i < N) ? deg[i] : 0;
  int v = (dv + 7) & ~7;                       // padded degree
  tmp[tid] = v;
  __syncthreads();
  for (int ofs = 1; ofs < 1024; ofs <<= 1) {
    int t = (tid >= ofs) ? tmp[tid - ofs] : 0;
    __syncthreads();
    tmp[tid] += t;
    __syncthreads();
  }
  if (i < N) part[i] = tmp[tid] - v;
  if (tid == 1023) bsum[blockIdx.x] = tmp[tid];
}

// -------- scan finalize + write pad records inline (no memsets) --------
__global__ void k_scan2(int* __restrict__ part, const int* __restrict__ bsum,
                        const int* __restrict__ deg, int N, int* __restrict__ cursor,
                        int4* __restrict__ csrp) {
  __shared__ int sbase;
  if (threadIdx.x == 0) {
    int b = 0;
    for (int j = 0; j < (int)blockIdx.x; j++) b += bsum[j];
    sbase = b;
  }
  __syncthreads();
  int i = blockIdx.x * 1024 + threadIdx.x;
  if (i < N) {
    const int o = part[i] + sbase;
    part[i] = o;                               // part == offsets
    cursor[i] = o;
    const int d = deg[i];
    const int pe = o + ((d + 7) & ~7);
    const int4 z = make_int4(0, 0, 0, 0);      // att=0 -> no contribution
    for (int s = o + d; s < pe; s++) csrp[s] = z;
    if (i == N - 1) part[N] = pe;
  }
}

// -------- fill: att edge-order, packed {src,e,att(bf16x4)} scatter; 2-edge unroll --
__launch_bounds__(256)
__global__ void k_fillP(const int* __restrict__ esrc, const int* __restrict__ edst, int E,
                        const float* __restrict__ ea, const float4* __restrict__ A_s,
                        const float4* __restrict__ A_d, const float* __restrict__ W_att,
                        int* __restrict__ cursor, int4* __restrict__ csrp) {
  __shared__ float4 s_we[32];                  // W_att[:,128:160]: 4 heads x 8 float4
  if (threadIdx.x < 32) {
    int h = threadIdx.x >> 3, k4 = threadIdx.x & 7;
    const float* p = &W_att[h * 160 + 128 + k4 * 4];
    s_we[threadIdx.x] = make_float4(p[0], p[1], p[2], p[3]);
  }
  __syncthreads();
  const int stride = gridDim.x * blockDim.x;
  for (int e1 = blockIdx.x * blockDim.x + threadIdx.x; e1 < E; e1 += 2 * stride) {
    const int e2 = e1 + stride;
    const bool has2 = (e2 < E);
    const int e2c = has2 ? e2 : e1;
    // independent chains for both edges, issued together
    const int s1 = esrc[e1], d1 = edst[e1];
    const int s2 = esrc[e2c], d2 = edst[e2c];
    const int slot1 = atomicAdd(&cursor[d1], 1);
    const int slot2 = has2 ? atomicAdd(&cursor[d2], 1) : 0;
    const float4 as1 = A_s[s1], ad1 = A_d[d1];
    const float4 as2 = A_s[s2], ad2 = A_d[d2];
    float lgA0 = as1.x + ad1.x, lgA1 = as1.y + ad1.y;
    float lgA2 = as1.z + ad1.z, lgA3 = as1.w + ad1.w;
    float lgB0 = as2.x + ad2.x, lgB1 = as2.y + ad2.y;
    float lgB2 = as2.z + ad2.z, lgB3 = as2.w + ad2.w;
    const float4* ep1 = (const float4*)&ea[(unsigned)e1 * 32u];
    const float4* ep2 = (const float4*)&ea[(unsigned)e2c * 32u];
    #pragma unroll
    for (int k = 0; k < 8; k++) {              // stream: one eq live per edge
      const float4 q1 = ep1[k];
      const float4 q2 = ep2[k];
      lgA0 += dot4(s_we[0 * 8 + k], q1); lgB0 += dot4(s_we[0 * 8 + k], q2);
      lgA1 += dot4(s_we[1 * 8 + k], q1); lgB1 += dot4(s_we[1 * 8 + k], q2);
      lgA2 += dot4(s_we[2 * 8 + k], q1); lgB2 += dot4(s_we[2 * 8 + k], q2);
      lgA3 += dot4(s_we[3 * 8 + k], q1); lgB3 += dot4(s_we[3 * 8 + k], q2);
    }
    lgA0 = fmaxf(lgA0, 0.2f * lgA0); lgA1 = fmaxf(lgA1, 0.2f * lgA1);
    lgA2 = fmaxf(lgA2, 0.2f * lgA2); lgA3 = fmaxf(lgA3, 0.2f * lgA3);
    lgB0 = fmaxf(lgB0, 0.2f * lgB0); lgB1 = fmaxf(lgB1, 0.2f * lgB1);
    lgB2 = fmaxf(lgB2, 0.2f * lgB2); lgB3 = fmaxf(lgB3, 0.2f * lgB3);
    csrp[slot1] = make_int4(s1, e1,
                            (int)pk2(__expf(lgA0), __expf(lgA1)),
                            (int)pk2(__expf(lgA2), __expf(lgA3)));
    if (has2)
      csrp[slot2] = make_int4(s2, e2,
                              (int)pk2(__expf(lgB0), __expf(lgB1)),
                              (int)pk2(__expf(lgB2), __expf(lgB3)));
  }
}

// -------- aggregation: quad-batched gathers (32 edges in flight per wave) --------
__launch_bounds__(256)
__global__ void k_aggP(const unsigned short* __restrict__ xb, const float* __restrict__ ea,
                       const int4* __restrict__ csrp, const int* __restrict__ offsets,
                       unsigned short* __restrict__ agg, float* __restrict__ denom, int N) {
  __shared__ int4 s_ids[4][32];                // wave-private slot quad
  const int lane = threadIdx.x & 63;
  const int wvb = threadIdx.x >> 6;
  const int wv = (blockIdx.x * blockDim.x + threadIdx.x) >> 6;
  const int nw = (gridDim.x * blockDim.x) >> 6;
  const int l32 = lane & 31;
  const bool hi = lane >= 32;

  for (int v0 = wv; v0 < N; v0 += nw) {
    const int vv = __builtin_amdgcn_readfirstlane(v0);
    const int sstart = __builtin_amdgcn_readfirstlane(offsets[vv]);
    const int send = __builtin_amdgcn_readfirstlane(offsets[vv + 1]);
    const int ng = (send - sstart) >> 3;       // 8-edge chunks (padded)
    const int nq = (ng + 3) >> 2;              // 32-edge quads

    float ax0 = 0, ax1 = 0, ax2 = 0, ax3 = 0;
    float ae0 = 0, ae1 = 0, ae2 = 0, ae3 = 0;
    float dn0 = 0, dn1 = 0, dn2 = 0, dn3 = 0;

    for (int q = 0; q < nq; q++) {
      {
        int4 q_ = csrp[sstart + q * 32 + l32];
        if (lane < 32) s_ids[wvb][l32] = q_;
      }
      const int nsc = min(4, ng - q * 4);      // live sub-chunks in this quad
      float ev[4][8];
      unsigned short qv[4][8];
      // ---- issue ALL gathers for the quad (up to 64 loads in flight) ----
      #pragma unroll
      for (int sc = 0; sc < 4; sc++) {
        if (sc < nsc) {
          #pragma unroll
          for (int p = 0; p < 8; p++) {
            const int4 t_ = s_ids[wvb][sc * 8 + p];
            qv[sc][p] = xb[(unsigned)(t_.x << 6) + lane];
            ev[sc][p] = ea[(unsigned)(t_.y << 5) + l32];
          }
        }
      }
      // ---- consume ----
      #pragma unroll
      for (int sc = 0; sc < 4; sc++) {
        if (sc < nsc) {
          #pragma unroll
          for (int p = 0; p < 8; p++) {
            const int4 t_ = s_ids[wvb][sc * 8 + p];   // b64 att re-read (broadcast)
            const float a0_ = ubf_lo((unsigned)t_.z);
            const float a1_ = ubf_hi((unsigned)t_.z);
            const float a2_ = ubf_lo((unsigned)t_.w);
            const float a3_ = ubf_hi((unsigned)t_.w);
            const float xf = ubf((unsigned)qv[sc][p]);
            const float evp = ev[sc][p];
            ax0 = fmaf(a0_, xf, ax0); ax1 = fmaf(a1_, xf, ax1);
            ax2 = fmaf(a2_, xf, ax2); ax3 = fmaf(a3_, xf, ax3);
            ae0 = fmaf(a0_, evp, ae0); ae1 = fmaf(a1_, evp, ae1);
            ae2 = fmaf(a2_, evp, ae2); ae3 = fmaf(a3_, evp, ae3);
            dn0 += a0_; dn1 += a1_; dn2 += a2_; dn3 += a3_;
          }
        }
      }
    }

    const unsigned base = (unsigned)v0 * 384u;
    agg[base + lane]        = fbf(ax0);
    agg[base + 96 + lane]   = fbf(ax1);
    agg[base + 192 + lane]  = fbf(ax2);
    agg[base + 288 + lane]  = fbf(ax3);
    const int hA = hi ? 2 : 0;
    agg[base + hA * 96 + 64 + l32]       = fbf(hi ? ae2 : ae0);
    agg[base + (hA + 1) * 96 + 64 + l32] = fbf(hi ? ae3 : ae1);
    if (lane == 0) ((float4*)denom)[v0] = make_float4(dn0, dn1, dn2, dn3);
  }
}

// ---------------- out = blockdiag(W_msg) * agg, /denom, +bias, LN ----------------
__launch_bounds__(128)
__global__ void k_out(const unsigned short* __restrict__ agg, const float* __restrict__ W_msg,
                      const float* __restrict__ denom, const float* __restrict__ bias,
                      const float* __restrict__ gamma, const float* __restrict__ beta,
                      float* __restrict__ out, int N, int T) {
  __shared__ float s_den[64];
  __shared__ float s_sum[2][16], s_sq[2][16];
  const int f = threadIdx.x;
  const int w = f >> 6;            // wave: heads 2w, 2w+1 -> cols 64w..64w+63
  const int l = f & 63;
  const int c16 = l & 15;
  const int rg = l >> 4;

  short8 wb[2][2][3];
  float biasv[2][2], gv[2][2], bv[2][2];
  #pragma unroll
  for (int hh = 0; hh < 2; hh++) {
    const int head = 2 * w + hh;
    #pragma unroll
    for (int ct = 0; ct < 2; ct++) {
      const int q = head * 32 + ct * 16 + c16;
      biasv[hh][ct] = bias[q]; gv[hh][ct] = gamma[q]; bv[hh][ct] = beta[q];
      #pragma unroll
      for (int kk = 0; kk < 3; kk++) {
        const float* p = &W_msg[q * 96 + kk * 32 + rg * 8];
        short8 s;
        #pragma unroll
        for (int i = 0; i < 8; i++) s[i] = (short)fbf(p[i]);
        wb[hh][ct][kk] = s;
      }
    }
  }

  for (int t = blockIdx.x; t < T; t += gridDim.x) {
    const int n0 = t * 16;
    if (f < 64) s_den[f] = denom[min(n0 + (f >> 2), N - 1) * 4 + (f & 3)];
    __syncthreads();

    f32x4 c[2][2] = {{{0.f,0.f,0.f,0.f},{0.f,0.f,0.f,0.f}},
                     {{0.f,0.f,0.f,0.f},{0.f,0.f,0.f,0.f}}};
    const int nA = min(n0 + c16, N - 1);
    #pragma unroll
    for (int hh = 0; hh < 2; hh++) {
      const int head = 2 * w + hh;
      #pragma unroll
      for (int kk = 0; kk < 3; kk++) {
        short8 a = *(const short8*)&agg[nA * 384 + head * 96 + kk * 32 + rg * 8];
        c[hh][0] = __builtin_amdgcn_mfma_f32_16x16x32_bf16(a, wb[hh][0][kk], c[hh][0], 0, 0, 0);
        c[hh][1] = __builtin_amdgcn_mfma_f32_16x16x32_bf16(a, wb[hh][1][kk], c[hh][1], 0, 0, 0);
      }
    }

    float val[2][2][4];
    #pragma unroll
    for (int hh = 0; hh < 2; hh++)
      #pragma unroll
      for (int ct = 0; ct < 2; ct++)
        #pragma unroll
        for (int r = 0; r < 4; r++) {
          const float d = s_den[(rg * 4 + r) * 4 + (2 * w + hh)] + 1e-9f;
          val[hh][ct][r] = c[hh][ct][r] / d + biasv[hh][ct];
        }

    float sr[4], qr[4];
    #pragma unroll
    for (int r = 0; r < 4; r++) {
      float s = 0.f, q2 = 0.f;
      #pragma unroll
      for (int hh = 0; hh < 2; hh++)
        #pragma unroll
        for (int ct = 0; ct < 2; ct++) { s += val[hh][ct][r]; q2 = fmaf(val[hh][ct][r], val[hh][ct][r], q2); }
      #pragma unroll
      for (int m = 1; m <= 8; m <<= 1) { s += __shfl_xor(s, m, 64); q2 += __shfl_xor(q2, m, 64); }
      sr[r] = s; qr[r] = q2;
    }
    if (c16 == 0) {
      #pragma unroll
      for (int r = 0; r < 4; r++) { s_sum[w][rg * 4 + r] = sr[r]; s_sq[w][rg * 4 + r] = qr[r]; }
    }
    __syncthreads();

    float mean[4], rstd[4];
    #pragma unroll
    for (int r = 0; r < 4; r++) {
      const int ni = rg * 4 + r;
      mean[r] = (s_sum[0][ni] + s_sum[1][ni]) * (1.f / 128.f);
      const float m2 = (s_sq[0][ni] + s_sq[1][ni]) * (1.f / 128.f);
      rstd[r] = rsqrtf(m2 - mean[r] * mean[r] + 1e-5f);
    }
    #pragma unroll
    for (int hh = 0; hh < 2; hh++)
      #pragma unroll
      for (int ct = 0; ct < 2; ct++)
        #pragma unroll
        for (int r = 0; r < 4; r++) {
          const int n = n0 + rg * 4 + r;
          if (n < N)
            out[n * 128 + (2 * w + hh) * 32 + ct * 16 + c16] =
                (val[hh][ct][r] - mean[r]) * rstd[r] * gv[hh][ct] + bv[hh][ct];
        }
    __syncthreads();
  }
}

extern "C" void kernel_launch(void* const* d_in, const int* in_sizes, int n_in,
                              void* d_out, int out_size, void* d_ws, size_t ws_size,
                              hipStream_t stream) {
  const float* x     = (const float*)d_in[0];
  const int*   ei    = (const int*)d_in[1];
  const float* ea    = (const float*)d_in[2];
  const float* W_msg = (const float*)d_in[3];
  const float* W_att = (const float*)d_in[4];
  const float* bias  = (const float*)d_in[5];
  const float* gamma = (const float*)d_in[6];
  const float* beta  = (const float*)d_in[7];
  float* out = (float*)d_out;

  const int N = in_sizes[0] / 64;
  const int E = in_sizes[1] / 2;
  const int* esrc = ei;
  const int* edst = ei + E;
  const int EP = E + 8 * N + 64;               // padded-CSR capacity

  char* p = (char*)d_ws;
  int* deg      = (int*)p;            p += (size_t)N * 4;
  int* offsets  = (int*)p;            p += (size_t)(N + 1) * 4;
  int* cursor   = (int*)p;            p += (size_t)N * 4;
  int* bsum     = (int*)p;            p += 2048 * 4;
  int4* csrp    = (int4*)p;           p += (size_t)EP * 16;
  float4* A_s   = (float4*)p;         p += (size_t)N * 16;
  float4* A_d   = (float4*)p;         p += (size_t)N * 16;
  unsigned short* xb = (unsigned short*)p; p += (size_t)N * 64 * 2;
  unsigned short* agg = (unsigned short*)p; p += (size_t)N * 384 * 2;
  float* denom  = (float*)p;

  hipMemsetAsync(deg, 0, (size_t)N * 4, stream);
  const int SB = (N + 1023) / 1024;
  const int T = (N + 15) / 16;

  k_phase1<<<2048, 256, 0, stream>>>(x, W_att, edst, E, A_s, A_d, (unsigned*)xb, deg, N);
  k_scan1<<<SB, 1024, 0, stream>>>(deg, N, offsets, bsum);
  k_scan2<<<SB, 1024, 0, stream>>>(offsets, bsum, deg, N, cursor, csrp);
  k_fillP<<<2048, 256, 0, stream>>>(esrc, edst, E, ea, A_s, A_d, W_att, cursor, csrp);
  k_aggP<<<2048, 256, 0, stream>>>(xb, ea, csrp, offsets, agg, denom, N);
  k_out<<<T, 128, 0, stream>>>(agg, W_msg, denom, bias, gamma, beta, out, N, T);
}

// Round 13
// 393.564 us; speedup vs baseline: 1.0580x; 1.0580x over previous
//
#include <hip/hip_runtime.h>
#include <hip/hip_bf16.h>

typedef __attribute__((ext_vector_type(8))) short short8;
typedef __attribute__((ext_vector_type(4))) float f32x4;

__device__ __forceinline__ unsigned short fbf(float f) {
  union { float f; unsigned u; } v; v.f = f;
  unsigned r = v.u + 0x7fffu + ((v.u >> 16) & 1u);   // RNE
  return (unsigned short)(r >> 16);
}
__device__ __forceinline__ unsigned pk2(float a, float b) {
  return (unsigned)fbf(a) | ((unsigned)fbf(b) << 16);
}
__device__ __forceinline__ float ubf(unsigned hi) {   // bf16 bits (low16) -> float
  union { unsigned u; float f; } v; v.u = hi << 16; return v.f;
}
__device__ __forceinline__ float ubf_lo(unsigned u) { // low16 bf16 -> float
  union { unsigned u; float f; } v; v.u = u << 16; return v.f;
}
__device__ __forceinline__ float ubf_hi(unsigned u) { // high16 bf16 -> float
  union { unsigned u; float f; } v; v.u = u & 0xffff0000u; return v.f;
}
__device__ __forceinline__ float dot4(float4 a, float4 b) {
  return fmaf(a.x, b.x, fmaf(a.y, b.y, fmaf(a.z, b.z, a.w * b.w)));
}

// -- phase1: degree count (rank kept!) + A_s/A_d tables + x->bf16 (single x pass) --
__launch_bounds__(256)
__global__ void k_phase1(const float* __restrict__ x, const float* __restrict__ W_att,
                         const int* __restrict__ edst, int E,
                         float4* __restrict__ A_s, float4* __restrict__ A_d,
                         unsigned* __restrict__ xb32, int* __restrict__ deg,
                         int* __restrict__ rank, int N) {
  __shared__ float4 s_wa[160];                 // 4 heads x 40 float4 (row len 160)
  if (threadIdx.x < 160) s_wa[threadIdx.x] = ((const float4*)W_att)[threadIdx.x];
  for (int i = blockIdx.x * blockDim.x + threadIdx.x; i < E; i += gridDim.x * blockDim.x)
    rank[i] = atomicAdd(&deg[edst[i]], 1);     // rank within destination: free
  __syncthreads();
  for (int v = blockIdx.x * blockDim.x + threadIdx.x; v < N; v += gridDim.x * blockDim.x) {
    const float4* xp = (const float4*)&x[v * 64];
    float4 xq[16];
    #pragma unroll
    for (int k = 0; k < 16; k++) xq[k] = xp[k];
    float as[4] = {}, ad[4] = {};
    #pragma unroll
    for (int h = 0; h < 4; h++) {
      #pragma unroll
      for (int k = 0; k < 16; k++) {
        as[h] += dot4(s_wa[h * 40 + k], xq[k]);
        ad[h] += dot4(s_wa[h * 40 + 16 + k], xq[k]);
      }
    }
    A_s[v] = make_float4(as[0], as[1], as[2], as[3]);
    A_d[v] = make_float4(ad[0], ad[1], ad[2], ad[3]);
    #pragma unroll
    for (int k = 0; k < 16; k++) {
      xb32[v * 32 + 2 * k]     = pk2(xq[k].x, xq[k].y);
      xb32[v * 32 + 2 * k + 1] = pk2(xq[k].z, xq[k].w);
    }
  }
}

// -------- scans over PADDED degrees (each node region rounded to mult of 8) --------
__global__ void k_scan1(const int* __restrict__ deg, int N, int* __restrict__ part,
                        int* __restrict__ bsum) {
  __shared__ int tmp[1024];
  int tid = threadIdx.x;
  int i = blockIdx.x * 1024 + tid;
  int dv = (i < N) ? deg[i] : 0;
  int v = (dv + 7) & ~7;                       // padded degree
  tmp[tid] = v;
  __syncthreads();
  for (int ofs = 1; ofs < 1024; ofs <<= 1) {
    int t = (tid >= ofs) ? tmp[tid - ofs] : 0;
    __syncthreads();
    tmp[tid] += t;
    __syncthreads();
  }
  if (i < N) part[i] = tmp[tid] - v;
  if (tid == 1023) bsum[blockIdx.x] = tmp[tid];
}

// -------- scan finalize + write pad records inline (no memsets) --------
__global__ void k_scan2(int* __restrict__ part, const int* __restrict__ bsum,
                        const int* __restrict__ deg, int N, int4* __restrict__ csrp) {
  __shared__ int sbase;
  if (threadIdx.x == 0) {
    int b = 0;
    for (int j = 0; j < (int)blockIdx.x; j++) b += bsum[j];
    sbase = b;
  }
  __syncthreads();
  int i = blockIdx.x * 1024 + threadIdx.x;
  if (i < N) {
    const int o = part[i] + sbase;
    part[i] = o;                               // part == offsets
    const int d = deg[i];
    const int pe = o + ((d + 7) & ~7);
    const int4 z = make_int4(0, 0, 0, 0);      // att=0 -> no contribution
    for (int s = o + d; s < pe; s++) csrp[s] = z;
    if (i == N - 1) part[N] = pe;
  }
}

// -------- fill: att edge-order; slot = offsets[d] + rank[e]; NO atomic --------
__launch_bounds__(256)
__global__ void k_fillP(const int* __restrict__ esrc, const int* __restrict__ edst, int E,
                        const float* __restrict__ ea, const float4* __restrict__ A_s,
                        const float4* __restrict__ A_d, const float* __restrict__ W_att,
                        const int* __restrict__ offsets, const int* __restrict__ rank,
                        int4* __restrict__ csrp) {
  __shared__ float4 s_we[32];                  // W_att[:,128:160]: 4 heads x 8 float4
  if (threadIdx.x < 32) {
    int h = threadIdx.x >> 3, k4 = threadIdx.x & 7;
    const float* p = &W_att[h * 160 + 128 + k4 * 4];
    s_we[threadIdx.x] = make_float4(p[0], p[1], p[2], p[3]);
  }
  __syncthreads();
  for (int e = blockIdx.x * blockDim.x + threadIdx.x; e < E; e += gridDim.x * blockDim.x) {
    const int s = esrc[e], d = edst[e];
    const int slot = offsets[d] + rank[e];     // no atomic in the chain
    const float4* ep = (const float4*)&ea[(unsigned)e * 32u];
    float4 eq[8];
    #pragma unroll
    for (int k = 0; k < 8; k++) eq[k] = ep[k];
    const float4 as4 = A_s[s], ad4 = A_d[d];
    const float base[4] = {as4.x + ad4.x, as4.y + ad4.y, as4.z + ad4.z, as4.w + ad4.w};
    float av[4];
    #pragma unroll
    for (int h = 0; h < 4; h++) {
      float lg = base[h];
      #pragma unroll
      for (int k = 0; k < 8; k++) lg += dot4(s_we[h * 8 + k], eq[k]);
      lg = fmaxf(lg, 0.2f * lg);               // leaky relu
      av[h] = __expf(lg);
    }
    csrp[slot] = make_int4(s, e, (int)pk2(av[0], av[1]), (int)pk2(av[2], av[3]));
  }
}

// -------- aggregation: quad-batched gathers (32 edges in flight per wave) --------
__launch_bounds__(256)
__global__ void k_aggP(const unsigned short* __restrict__ xb, const float* __restrict__ ea,
                       const int4* __restrict__ csrp, const int* __restrict__ offsets,
                       unsigned short* __restrict__ agg, float* __restrict__ denom, int N) {
  __shared__ int4 s_ids[4][32];                // wave-private slot quad
  const int lane = threadIdx.x & 63;
  const int wvb = threadIdx.x >> 6;
  const int wv = (blockIdx.x * blockDim.x + threadIdx.x) >> 6;
  const int nw = (gridDim.x * blockDim.x) >> 6;
  const int l32 = lane & 31;
  const bool hi = lane >= 32;

  for (int v0 = wv; v0 < N; v0 += nw) {
    const int vv = __builtin_amdgcn_readfirstlane(v0);
    const int sstart = __builtin_amdgcn_readfirstlane(offsets[vv]);
    const int send = __builtin_amdgcn_readfirstlane(offsets[vv + 1]);
    const int ng = (send - sstart) >> 3;       // 8-edge chunks (padded)
    const int nq = (ng + 3) >> 2;              // 32-edge quads

    float ax0 = 0, ax1 = 0, ax2 = 0, ax3 = 0;
    float ae0 = 0, ae1 = 0, ae2 = 0, ae3 = 0;
    float dn0 = 0, dn1 = 0, dn2 = 0, dn3 = 0;

    for (int q = 0; q < nq; q++) {
      {
        int4 q_ = csrp[sstart + q * 32 + l32];
        if (lane < 32) s_ids[wvb][l32] = q_;
      }
      const int nsc = min(4, ng - q * 4);      // live sub-chunks in this quad
      float ev[4][8];
      unsigned short qv[4][8];
      // ---- issue ALL gathers for the quad (up to 64 loads in flight) ----
      #pragma unroll
      for (int sc = 0; sc < 4; sc++) {
        if (sc < nsc) {
          #pragma unroll
          for (int p = 0; p < 8; p++) {
            const int4 t_ = s_ids[wvb][sc * 8 + p];
            qv[sc][p] = xb[(unsigned)(t_.x << 6) + lane];
            ev[sc][p] = ea[(unsigned)(t_.y << 5) + l32];
          }
        }
      }
      // ---- consume ----
      #pragma unroll
      for (int sc = 0; sc < 4; sc++) {
        if (sc < nsc) {
          #pragma unroll
          for (int p = 0; p < 8; p++) {
            const int4 t_ = s_ids[wvb][sc * 8 + p];   // b64 att re-read (broadcast)
            const float a0_ = ubf_lo((unsigned)t_.z);
            const float a1_ = ubf_hi((unsigned)t_.z);
            const float a2_ = ubf_lo((unsigned)t_.w);
            const float a3_ = ubf_hi((unsigned)t_.w);
            const float xf = ubf((unsigned)qv[sc][p]);
            const float evp = ev[sc][p];
            ax0 = fmaf(a0_, xf, ax0); ax1 = fmaf(a1_, xf, ax1);
            ax2 = fmaf(a2_, xf, ax2); ax3 = fmaf(a3_, xf, ax3);
            ae0 = fmaf(a0_, evp, ae0); ae1 = fmaf(a1_, evp, ae1);
            ae2 = fmaf(a2_, evp, ae2); ae3 = fmaf(a3_, evp, ae3);
            dn0 += a0_; dn1 += a1_; dn2 += a2_; dn3 += a3_;
          }
        }
      }
    }

    const unsigned base = (unsigned)v0 * 384u;
    agg[base + lane]        = fbf(ax0);
    agg[base + 96 + lane]   = fbf(ax1);
    agg[base + 192 + lane]  = fbf(ax2);
    agg[base + 288 + lane]  = fbf(ax3);
    const int hA = hi ? 2 : 0;
    agg[base + hA * 96 + 64 + l32]       = fbf(hi ? ae2 : ae0);
    agg[base + (hA + 1) * 96 + 64 + l32] = fbf(hi ? ae3 : ae1);
    if (lane == 0) ((float4*)denom)[v0] = make_float4(dn0, dn1, dn2, dn3);
  }
}

// ---------------- out = blockdiag(W_msg) * agg, /denom, +bias, LN ----------------
__launch_bounds__(128)
__global__ void k_out(const unsigned short* __restrict__ agg, const float* __restrict__ W_msg,
                      const float* __restrict__ denom, const float* __restrict__ bias,
                      const float* __restrict__ gamma, const float* __restrict__ beta,
                      float* __restrict__ out, int N, int T) {
  __shared__ float s_den[64];
  __shared__ float s_sum[2][16], s_sq[2][16];
  const int f = threadIdx.x;
  const int w = f >> 6;            // wave: heads 2w, 2w+1 -> cols 64w..64w+63
  const int l = f & 63;
  const int c16 = l & 15;
  const int rg = l >> 4;

  short8 wb[2][2][3];
  float biasv[2][2], gv[2][2], bv[2][2];
  #pragma unroll
  for (int hh = 0; hh < 2; hh++) {
    const int head = 2 * w + hh;
    #pragma unroll
    for (int ct = 0; ct < 2; ct++) {
      const int q = head * 32 + ct * 16 + c16;
      biasv[hh][ct] = bias[q]; gv[hh][ct] = gamma[q]; bv[hh][ct] = beta[q];
      #pragma unroll
      for (int kk = 0; kk < 3; kk++) {
        const float* p = &W_msg[q * 96 + kk * 32 + rg * 8];
        short8 s;
        #pragma unroll
        for (int i = 0; i < 8; i++) s[i] = (short)fbf(p[i]);
        wb[hh][ct][kk] = s;
      }
    }
  }

  for (int t = blockIdx.x; t < T; t += gridDim.x) {
    const int n0 = t * 16;
    if (f < 64) s_den[f] = denom[min(n0 + (f >> 2), N - 1) * 4 + (f & 3)];
    __syncthreads();

    f32x4 c[2][2] = {{{0.f,0.f,0.f,0.f},{0.f,0.f,0.f,0.f}},
                     {{0.f,0.f,0.f,0.f},{0.f,0.f,0.f,0.f}}};
    const int nA = min(n0 + c16, N - 1);
    #pragma unroll
    for (int hh = 0; hh < 2; hh++) {
      const int head = 2 * w + hh;
      #pragma unroll
      for (int kk = 0; kk < 3; kk++) {
        short8 a = *(const short8*)&agg[nA * 384 + head * 96 + kk * 32 + rg * 8];
        c[hh][0] = __builtin_amdgcn_mfma_f32_16x16x32_bf16(a, wb[hh][0][kk], c[hh][0], 0, 0, 0);
        c[hh][1] = __builtin_amdgcn_mfma_f32_16x16x32_bf16(a, wb[hh][1][kk], c[hh][1], 0, 0, 0);
      }
    }

    float val[2][2][4];
    #pragma unroll
    for (int hh = 0; hh < 2; hh++)
      #pragma unroll
      for (int ct = 0; ct < 2; ct++)
        #pragma unroll
        for (int r = 0; r < 4; r++) {
          const float d = s_den[(rg * 4 + r) * 4 + (2 * w + hh)] + 1e-9f;
          val[hh][ct][r] = c[hh][ct][r] / d + biasv[hh][ct];
        }

    float sr[4], qr[4];
    #pragma unroll
    for (int r = 0; r < 4; r++) {
      float s = 0.f, q2 = 0.f;
      #pragma unroll
      for (int hh = 0; hh < 2; hh++)
        #pragma unroll
        for (int ct = 0; ct < 2; ct++) { s += val[hh][ct][r]; q2 = fmaf(val[hh][ct][r], val[hh][ct][r], q2); }
      #pragma unroll
      for (int m = 1; m <= 8; m <<= 1) { s += __shfl_xor(s, m, 64); q2 += __shfl_xor(q2, m, 64); }
      sr[r] = s; qr[r] = q2;
    }
    if (c16 == 0) {
      #pragma unroll
      for (int r = 0; r < 4; r++) { s_sum[w][rg * 4 + r] = sr[r]; s_sq[w][rg * 4 + r] = qr[r]; }
    }
    __syncthreads();

    float mean[4], rstd[4];
    #pragma unroll
    for (int r = 0; r < 4; r++) {
      const int ni = rg * 4 + r;
      mean[r] = (s_sum[0][ni] + s_sum[1][ni]) * (1.f / 128.f);
      const float m2 = (s_sq[0][ni] + s_sq[1][ni]) * (1.f / 128.f);
      rstd[r] = rsqrtf(m2 - mean[r] * mean[r] + 1e-5f);
    }
    #pragma unroll
    for (int hh = 0; hh < 2; hh++)
      #pragma unroll
      for (int ct = 0; ct < 2; ct++)
        #pragma unroll
        for (int r = 0; r < 4; r++) {
          const int n = n0 + rg * 4 + r;
          if (n < N)
            out[n * 128 + (2 * w + hh) * 32 + ct * 16 + c16] =
                (val[hh][ct][r] - mean[r]) * rstd[r] * gv[hh][ct] + bv[hh][ct];
        }
    __syncthreads();
  }
}

extern "C" void kernel_launch(void* const* d_in, const int* in_sizes, int n_in,
                              void* d_out, int out_size, void* d_ws, size_t ws_size,
                              hipStream_t stream) {
  const float* x     = (const float*)d_in[0];
  const int*   ei    = (const int*)d_in[1];
  const float* ea    = (const float*)d_in[2];
  const float* W_msg = (const float*)d_in[3];
  const float* W_att = (const float*)d_in[4];
  const float* bias  = (const float*)d_in[5];
  const float* gamma = (const float*)d_in[6];
  const float* beta  = (const float*)d_in[7];
  float* out = (float*)d_out;

  const int N = in_sizes[0] / 64;
  const int E = in_sizes[1] / 2;
  const int* esrc = ei;
  const int* edst = ei + E;
  const int EP = E + 8 * N + 64;               // padded-CSR capacity

  char* p = (char*)d_ws;
  int* deg      = (int*)p;            p += (size_t)N * 4;
  int* offsets  = (int*)p;            p += (size_t)(N + 1) * 4;
  int* rank     = (int*)p;            p += (size_t)E * 4;
  int* bsum     = (int*)p;            p += 2048 * 4;
  int4* csrp    = (int4*)p;           p += (size_t)EP * 16;
  float4* A_s   = (float4*)p;         p += (size_t)N * 16;
  float4* A_d   = (float4*)p;         p += (size_t)N * 16;
  unsigned short* xb = (unsigned short*)p; p += (size_t)N * 64 * 2;
  unsigned short* agg = (unsigned short*)p; p += (size_t)N * 384 * 2;
  float* denom  = (float*)p;

  hipMemsetAsync(deg, 0, (size_t)N * 4, stream);
  const int SB = (N + 1023) / 1024;
  const int T = (N + 15) / 16;

  k_phase1<<<2048, 256, 0, stream>>>(x, W_att, edst, E, A_s, A_d, (unsigned*)xb, deg, rank, N);
  k_scan1<<<SB, 1024, 0, stream>>>(deg, N, offsets, bsum);
  k_scan2<<<SB, 1024, 0, stream>>>(offsets, bsum, deg, N, csrp);
  k_fillP<<<2048, 256, 0, stream>>>(esrc, edst, E, ea, A_s, A_d, W_att, offsets, rank, csrp);
  k_aggP<<<2048, 256, 0, stream>>>(xb, ea, csrp, offsets, agg, denom, N);
  k_out<<<T, 128, 0, stream>>>(agg, W_msg, denom, bias, gamma, beta, out, N, T);
}